// Round 8
// baseline (735.116 us; speedup 1.0000x reference)
//
#include <hip/hip_runtime.h>
#include <math.h>

#define NN 4096

typedef float4 f4;
typedef _Float16 f16;
typedef _Float16 f16x8 __attribute__((ext_vector_type(8)));
typedef _Float16 h4 __attribute__((ext_vector_type(4)));
typedef float f32x4v __attribute__((ext_vector_type(4)));

// adjmm-convention B-frag offset (f16 units): ch = output column, n = reduction (node)
__device__ __forceinline__ size_t frag_off(int CT, int ch, int n) {
  return ((size_t)(n >> 5) * CT + (ch >> 4)) * 512
       + (size_t)((((ch & 15) + (((n & 31) >> 3) << 4)) << 3) + (n & 7));
}
// n-convention B-frag (for wgemm): col = node n (4096 wide -> CT=256), k = feature
__device__ __forceinline__ size_t nfrag_off(int k, int n) {
  return ((size_t)(k >> 5) * 256 + (n >> 4)) * 512
       + (size_t)((((n & 15) + (((k & 31) >> 3) << 4)) << 3) + (k & 7));
}
// A-frag offset (weights, M=128): row o, reduction k
__device__ __forceinline__ size_t afrag_off(int K32, int o, int k) {
  return ((size_t)(o >> 4) * K32 + (k >> 5)) * 512
       + (size_t)((((o & 15) + (((k & 31) >> 3) << 4)) << 3) + (k & 7));
}

// ---------------- adj fp32 -> fp16 A-frags (LDS-staged, coalesced) + colsum partials -------
__global__ __launch_bounds__(256)
void convert_cs2(const float* __restrict__ adj, f16* __restrict__ adj16,
                 float* __restrict__ csp) {
  __shared__ f16 lds16[32][520];
  const int rb = blockIdx.x;        // 128 blocks of 32 rows
  const int cb = blockIdx.y;        // 8 col blocks of 512
  const int t = threadIdx.x;
  const int half = t >> 7;          // 2 row halves of 16
  const int u = t & 127;
  const int c0 = cb * 512 + u * 4;
  float cs0 = 0.f, cs1 = 0.f, cs2 = 0.f, cs3 = 0.f;
  #pragma unroll 4
  for (int r = 0; r < 16; ++r) {
    const int i = rb * 32 + half * 16 + r;
    f4 v = *(const f4*)(adj + (size_t)i * NN + c0);
    cs0 += v.x; cs1 += v.y; cs2 += v.z; cs3 += v.w;
    h4 hv; hv[0] = (f16)v.x; hv[1] = (f16)v.y; hv[2] = (f16)v.z; hv[3] = (f16)v.w;
    *(h4*)&lds16[half * 16 + r][u * 4] = hv;
  }
  f4 cv; cv.x = cs0; cv.y = cs1; cv.z = cs2; cv.w = cs3;
  *(f4*)(csp + (size_t)(rb * 2 + half) * NN + c0) = cv;
  __syncthreads();
  const int rt = rb * 2 + half;
  f16* dst = adj16 + ((size_t)rt * 128 + cb * 16) * 512;
  #pragma unroll
  for (int s = 0; s < 8; ++s) {
    const int e = s * 1024 + u * 8;
    const int bl = e >> 9;
    const int l = (e >> 3) & 63;
    const int row = half * 16 + (l & 15);
    const int col = bl * 32 + (l >> 4) * 8;
    f16x8 fr = *(const f16x8*)&lds16[row][col];
    *(f16x8*)(dst + e) = fr;
  }
}

__global__ void colsum_fin(const float* __restrict__ csp, float* __restrict__ deg_inv) {
  int j = blockIdx.x * 256 + threadIdx.x;
  float s = 0.f;
  for (int rb = 0; rb < 256; ++rb) s += csp[(size_t)rb * NN + j];
  deg_inv[j] = 1.0f / (s + 1e-6f);
}

// ---------------- weight fold 1: per (branch, tap) GEMM into wpart ----------------
__global__ __launch_bounds__(256)
void wfold1(const float* __restrict__ proj_w,
            const float* __restrict__ w0, const float* __restrict__ w1,
            const float* __restrict__ w2, const float* __restrict__ w3,
            float* __restrict__ wpart) {
  __shared__ float projs[128][65];
  __shared__ float wk[64][65];
  const int b = blockIdx.x;
  int br, kp;
  if (b == 0) { br = 0; kp = 0; }
  else if (b < 4) { br = 1; kp = b - 1; }
  else if (b < 9) { br = 2; kp = b - 4; }
  else { br = 3; kp = b - 9; }
  const int Kbr = 2 * br + 1;
  const float* Wbr = (br == 0) ? w0 : (br == 1) ? w1 : (br == 2) ? w2 : w3;
  const int baseo[4] = {0, 8192, 32768, 73728};
  const int t = threadIdx.x;
  #pragma unroll
  for (int r = 0; r < 32; ++r) {
    int e = r * 256 + t; int o = e >> 6, cp = e & 63;
    projs[o][cp] = proj_w[(size_t)o * 256 + br * 64 + cp];
  }
  #pragma unroll
  for (int r = 0; r < 16; ++r) {
    int e = r * 256 + t; int cp = e >> 6, c = e & 63;
    wk[cp][c] = Wbr[(size_t)(cp * 64 + c) * Kbr + kp];
  }
  __syncthreads();
  for (int i = 0; i < 32; ++i) {
    int e = i * 256 + t; int o = e >> 6, c = e & 63;
    float s = 0.f;
    #pragma unroll 8
    for (int cp = 0; cp < 64; ++cp) s += projs[o][cp] * wk[cp][c];
    wpart[baseo[br] + (size_t)(o * 64 + c) * Kbr + kp] = s;
  }
}

// ---------------- weight fold assemble: Weff[o][c][7] + beff ----------------
__global__ void wfold_asm(const float* __restrict__ wpart, const float* __restrict__ proj_w,
                          const float* __restrict__ proj_b,
                          const float* __restrict__ b0, const float* __restrict__ b1,
                          const float* __restrict__ b2, const float* __restrict__ b3,
                          float* __restrict__ Weff, float* __restrict__ beff) {
  const int id = blockIdx.x * 256 + threadIdx.x;
  const int o = id >> 6, c = id & 63;
  const int oc = o * 64 + c;
  #pragma unroll
  for (int k = 0; k < 7; ++k) {
    float s = 0.f;
    if (k == 3)            s += wpart[oc];
    if (k >= 2 && k <= 4)  s += wpart[8192  + oc * 3 + (k - 2)];
    if (k >= 1 && k <= 5)  s += wpart[32768 + oc * 5 + (k - 1)];
    s += wpart[73728 + oc * 7 + k];
    Weff[(size_t)oc * 7 + k] = s;
  }
  if (blockIdx.x == 0 && threadIdx.x < 128) {
    const int oo = threadIdx.x;
    float s = proj_b[oo];
    for (int j = 0; j < 64; ++j) {
      s += proj_w[(size_t)oo * 256 + j] * b0[j];
      s += proj_w[(size_t)oo * 256 + 64 + j] * b1[j];
      s += proj_w[(size_t)oo * 256 + 128 + j] * b2[j];
      s += proj_w[(size_t)oo * 256 + 192 + j] * b3[j];
    }
    beff[oo] = s;
  }
}

// ---------------- weight fold 2: Wcy = kur_wy @ Weff -> f16 A-frags; cyb ----------------
__global__ __launch_bounds__(256)
void wfold2(const float* __restrict__ kur_wy, const float* __restrict__ Weff,
            const float* __restrict__ beff, const float* __restrict__ kur_by,
            const float* __restrict__ kur_bc,
            f16* __restrict__ wcyfrag, float* __restrict__ cyb) {
  __shared__ float wyh[128][65];
  __shared__ float weffL[128][33];
  const int ckb = blockIdx.x * 32;
  const int t = threadIdx.x;
  const int o = t & 127, hh = t >> 7;
  #pragma unroll
  for (int r = 0; r < 16; ++r) {
    int e = r * 256 + t; int op = e >> 5, ck = e & 31;
    weffL[op][ck] = Weff[(size_t)op * 448 + ckb + ck];
  }
  float acc[16];
  #pragma unroll
  for (int i = 0; i < 16; ++i) acc[i] = 0.f;
  float bacc = 0.f;
  for (int h = 0; h < 2; ++h) {
    __syncthreads();
    #pragma unroll
    for (int r = 0; r < 32; ++r) {
      int e = r * 256 + t; int oo = e >> 6, o2 = e & 63;
      wyh[oo][o2] = kur_wy[(size_t)oo * 128 + h * 64 + o2];
    }
    __syncthreads();
    for (int oo = 0; oo < 64; ++oo) {
      float w = wyh[o][oo];
      int op = h * 64 + oo;
      #pragma unroll
      for (int i = 0; i < 16; ++i) acc[i] += w * weffL[op][hh * 16 + i];
      if (t < 128) bacc += w * beff[op];
    }
  }
  #pragma unroll
  for (int i = 0; i < 16; ++i) {
    int ck = ckb + hh * 16 + i;
    int c = ck / 7, kt = ck % 7;
    wcyfrag[afrag_off(14, o, kt * 64 + c)] = (f16)acc[i];
  }
  if (blockIdx.x == 0 && t < 128) cyb[t] = bacc + kur_by[t] + kur_bc[t];
}

// ---------------- convert pat_w / kur_wc / ro_w1 to f16 A-frags ----------------
__global__ void wprep(const float* __restrict__ pat_w, const float* __restrict__ kur_wc,
                      const float* __restrict__ ro_w1,
                      f16* __restrict__ patfrag, f16* __restrict__ wcfrag,
                      f16* __restrict__ row1frag) {
  const int id = blockIdx.x * 256 + threadIdx.x;
  if (id < 57344) {
    int o = id / 448, k = id % 448;
    patfrag[afrag_off(14, o, k)] = (f16)pat_w[id];
  } else if (id < 73728) {
    int e = id - 57344; int o = e >> 7, k = e & 127;
    wcfrag[afrag_off(4, o, k)] = (f16)kur_wc[e];
  } else {
    int e = id - 73728; int o = e >> 7, k = e & 127;
    row1frag[afrag_off(4, o, k)] = (f16)ro_w1[e];
  }
}

// ---------------- x[N,64] -> xT[64][N] + gst coef0 row + fragA0 (x*deg_inv) ----------------
__global__ void transpose_x(const float* __restrict__ x, const float* __restrict__ deg,
                            float* __restrict__ xT, float* __restrict__ gst,
                            f16* __restrict__ fragA) {
  __shared__ float T[64][65];
  const int nb = blockIdx.x * 64;
  const int t = threadIdx.x;
  #pragma unroll
  for (int r = 0; r < 16; ++r) {
    int e = r * 256 + t; int nl = e >> 6, f = e & 63;
    T[nl][f] = x[(size_t)(nb + nl) * 64 + f];
  }
  __syncthreads();
  #pragma unroll
  for (int r = 0; r < 16; ++r) {
    int e = r * 256 + t; int f = e >> 6, nl = e & 63;
    float v = T[nl][f];
    xT[(size_t)f * NN + nb + nl] = v;
    gst[(size_t)f * 7 * NN + nb + nl] = v;
  }
  #pragma unroll
  for (int k = 0; k < 2; ++k) {
    int fi = k * 256 + t;
    int f = fi >> 3, n0l = (fi & 7) << 3;
    f16x8 fr;
    #pragma unroll
    for (int j = 0; j < 8; ++j) fr[j] = (f16)(T[n0l + j][f] * deg[nb + n0l + j]);
    *(f16x8*)(fragA + frag_off(4, f, nb + n0l)) = fr;
  }
}

// ---------------- im2col: x -> n-frags [k = dk*64+c][n], zero-padded ----------------
__global__ void im2col(const float* __restrict__ x, f16* __restrict__ fragN) {
  const int ot = blockIdx.x * 256 + threadIdx.x;
  const int q = ot >> 12;
  const int n = ot & 4095;
  const int dk = q >> 3;
  const int c0 = (q & 7) * 8;
  const int np = n + dk - 3;
  f16x8 fr;
  if (np >= 0 && np < NN) {
    const float* src = x + (size_t)np * 64 + c0;
    f4 v0 = *(const f4*)src, v1 = *(const f4*)(src + 4);
    fr[0]=(f16)v0.x; fr[1]=(f16)v0.y; fr[2]=(f16)v0.z; fr[3]=(f16)v0.w;
    fr[4]=(f16)v1.x; fr[5]=(f16)v1.y; fr[6]=(f16)v1.z; fr[7]=(f16)v1.w;
  } else {
    #pragma unroll
    for (int j = 0; j < 8; ++j) fr[j] = (f16)0.f;
  }
  *(f16x8*)(fragN + nfrag_off(q * 8, n)) = fr;
}

// ---------------- full-K fused adj GEMM: block = 16 nodes x all F channels -------------
// 8 waves split K (512 each); 2-step LDS tree reduce; fused epilogue (P or Kuramoto).
// KUR=false: P epilogue (0.5*(u+s), fragNext, |D-o| -> s1/fragDiff/gstf).
// KUR=true : c = s + cy -> outp(cbuf); per-channel stats partials -> statp[ch*256+b].
template<int CT, bool KUR>
__global__ __launch_bounds__(512)
void adjfull(const f16* __restrict__ adj16, const f16* __restrict__ rhs,
             const float* __restrict__ u, const float* __restrict__ D,
             float* __restrict__ outp, f16* __restrict__ fragNext, int nextCT,
             f16* __restrict__ fragDiff, int diffChOff,
             float* __restrict__ gstf, int coefLo, int coefHi,
             float* __restrict__ s1, const float* __restrict__ deg,
             const float* __restrict__ cy, float* __restrict__ statp) {
  __shared__ float red[4 * CT * 256];
  const int t = threadIdx.x;
  const int lane = t & 63, w = t >> 6;
  const int b = blockIdx.x;
  const int kt0 = w * 16;
  const size_t aoff = ((size_t)b * 128 + kt0) * 512 + (size_t)lane * 8;
  const f16* bb = rhs + (size_t)kt0 * CT * 512 + lane * 8;
  f32x4v acc[CT];
  #pragma unroll
  for (int c = 0; c < CT; ++c) acc[c] = (f32x4v){0.f, 0.f, 0.f, 0.f};
  #pragma unroll 2
  for (int i = 0; i < 16; ++i) {
    f16x8 a = *(const f16x8*)(adj16 + aoff + (size_t)i * 512);
    #pragma unroll
    for (int c = 0; c < CT; ++c) {
      f16x8 bv = *(const f16x8*)(bb + ((size_t)i * CT + c) * 512);
      acc[c] = __builtin_amdgcn_mfma_f32_16x16x32_f16(a, bv, acc[c], 0, 0, 0);
    }
  }
  // step 1: waves 4-7 store
  if (w >= 4) {
    float* myw = red + (w - 4) * (CT * 256);
    #pragma unroll
    for (int c = 0; c < CT; ++c) *(f32x4v*)(myw + c * 256 + lane * 4) = acc[c];
  }
  __syncthreads();
  // step 2: waves 0-3 add partner and store
  if (w < 4) {
    float* myw = red + w * (CT * 256);
    #pragma unroll
    for (int c = 0; c < CT; ++c) {
      acc[c] += *(const f32x4v*)(myw + c * 256 + lane * 4);
      *(f32x4v*)(myw + c * 256 + lane * 4) = acc[c];
    }
  }
  __syncthreads();
  if (t >= CT * 64) return;
  const int ct = t >> 6, l = t & 63;
  const int slot = ct * 256 + l * 4;
  f32x4v v = *(const f32x4v*)(red + slot);
  v += *(const f32x4v*)(red + CT * 256 + slot);
  v += *(const f32x4v*)(red + 2 * CT * 256 + slot);
  v += *(const f32x4v*)(red + 3 * CT * 256 + slot);
  const int ch = ct * 16 + (l & 15);
  const int node0 = b * 16 + ((l >> 4) << 2);
  const size_t base = (size_t)ch * NN + node0;

  if constexpr (KUR) {
    f4 cyv = *(const f4*)(cy + base);
    float o0 = v[0] + cyv.x, o1 = v[1] + cyv.y, o2 = v[2] + cyv.z, o3 = v[3] + cyv.w;
    f4 ov; ov.x = o0; ov.y = o1; ov.z = o2; ov.w = o3;
    *(f4*)(outp + base) = ov;
    float s  = o0 + o1 + o2 + o3;
    float ss = o0*o0 + o1*o1 + o2*o2 + o3*o3;
    s  += __shfl_xor(s, 16);  ss += __shfl_xor(ss, 16);
    s  += __shfl_xor(s, 32);  ss += __shfl_xor(ss, 32);
    if ((l >> 4) == 0) {
      statp[(ch * 256 + b) * 2]     = s;
      statp[(ch * 256 + b) * 2 + 1] = ss;
    }
  } else {
    f4 u0 = *(const f4*)(u + base);
    float o[4];
    o[0] = 0.5f * (u0.x + v[0]); o[1] = 0.5f * (u0.y + v[1]);
    o[2] = 0.5f * (u0.z + v[2]); o[3] = 0.5f * (u0.w + v[3]);
    f4 ov; ov.x = o[0]; ov.y = o[1]; ov.z = o[2]; ov.w = o[3];
    *(f4*)(outp + base) = ov;
    if (fragNext) {
      f4 dg = *(const f4*)(deg + node0);
      h4 fr;
      fr[0] = (f16)(o[0] * dg.x); fr[1] = (f16)(o[1] * dg.y);
      fr[2] = (f16)(o[2] * dg.z); fr[3] = (f16)(o[3] * dg.w);
      *(h4*)(fragNext + frag_off(nextCT, ch, node0)) = fr;
    }
    if (D) {
      f4 d0 = *(const f4*)(D + base);
      float dd[4];
      dd[0] = fabsf(d0.x - o[0]); dd[1] = fabsf(d0.y - o[1]);
      dd[2] = fabsf(d0.z - o[2]); dd[3] = fabsf(d0.w - o[3]);
      f4 ev; ev.x = dd[0]; ev.y = dd[1]; ev.z = dd[2]; ev.w = dd[3];
      if (s1) *(f4*)(s1 + base) = ev;
      if (fragDiff) {
        f4 dg = *(const f4*)(deg + node0);
        h4 fr;
        fr[0] = (f16)(dd[0] * dg.x); fr[1] = (f16)(dd[1] * dg.y);
        fr[2] = (f16)(dd[2] * dg.z); fr[3] = (f16)(dd[3] * dg.w);
        *(h4*)(fragDiff + frag_off(8, diffChOff + ch, node0)) = fr;
      }
      if (gstf) {
        int coef = (ch < 64) ? coefLo : coefHi;
        if (coef >= 0)
          *(f4*)(gstf + (size_t)((ch & 63) * 7 + coef) * NN + node0) = ev;
      }
    }
  }
}

// ---------------- stats finalize: statp[128][256]{s,ss} -> gnst[32]{mu,rstd} --------------
__global__ void statsfin(const float* __restrict__ statp, float* __restrict__ gnst) {
  __shared__ float ls[128], lss[128];
  const int t = threadIdx.x;
  if (t < 128) {
    float s = 0.f, ss = 0.f;
    for (int b = 0; b < 256; ++b) {
      s  += statp[(t * 256 + b) * 2];
      ss += statp[(t * 256 + b) * 2 + 1];
    }
    ls[t] = s; lss[t] = ss;
  }
  __syncthreads();
  if (t < 32) {
    float s = ls[4*t] + ls[4*t+1] + ls[4*t+2] + ls[4*t+3];
    float ss = lss[4*t] + lss[4*t+1] + lss[4*t+2] + lss[4*t+3];
    float mu = s * (1.f / 16384.f);
    float var = ss * (1.f / 16384.f) - mu * mu;
    gnst[2*t] = mu;
    gnst[2*t+1] = rsqrtf(var + 1e-5f);
  }
}

// ---------------- gstf fp32 rows -> n-frags (LDS transpose) ----------------
__global__ void gst2frag(const float* __restrict__ gstf, f16* __restrict__ fragN) {
  __shared__ float T[64][65];
  const int nb = blockIdx.x * 64;
  const int kb = blockIdx.y * 64;
  const int t = threadIdx.x;
  #pragma unroll
  for (int r = 0; r < 16; ++r) {
    int e = r * 256 + t; int row = e >> 6, col = e & 63;
    T[row][col] = gstf[(size_t)(kb + row) * NN + nb + col];
  }
  __syncthreads();
  #pragma unroll
  for (int h = 0; h < 2; ++h) {
    int idx = h * 256 + t;
    int q = idx >> 6, n = idx & 63;
    f16x8 fr;
    #pragma unroll
    for (int j = 0; j < 8; ++j) fr[j] = (f16)T[q * 8 + j][n];
    *(f16x8*)(fragN + nfrag_off(kb + q * 8, nb + n)) = fr;
  }
}

// ---------------- generic MFMA wgemm (EPI 0/1/2/3 as before) ----------------
template<int K32, int EPI>
__global__ __launch_bounds__(256)
void wgemm(const f16* __restrict__ A, const f16* __restrict__ B,
           const float* __restrict__ bias, float* __restrict__ out,
           f16* __restrict__ ofrag) {
  const int t = threadIdx.x;
  const int lane = t & 63, w = t >> 6;
  const int nb = blockIdx.x * 32;
  const size_t a0b = ((size_t)(2 * w) * K32) * 512 + lane * 8;
  const size_t a1b = ((size_t)(2 * w + 1) * K32) * 512 + lane * 8;
  const size_t b0b = (size_t)(nb >> 4) * 512 + lane * 8;
  f32x4v acc[2][2];
  acc[0][0] = (f32x4v){0,0,0,0}; acc[0][1] = (f32x4v){0,0,0,0};
  acc[1][0] = (f32x4v){0,0,0,0}; acc[1][1] = (f32x4v){0,0,0,0};
  #pragma unroll
  for (int i = 0; i < K32; ++i) {
    f16x8 a0 = *(const f16x8*)(A + a0b + (size_t)i * 512);
    f16x8 a1 = *(const f16x8*)(A + a1b + (size_t)i * 512);
    f16x8 b0 = *(const f16x8*)(B + b0b + (size_t)i * 256 * 512);
    f16x8 b1 = *(const f16x8*)(B + b0b + (size_t)i * 256 * 512 + 512);
    acc[0][0] = __builtin_amdgcn_mfma_f32_16x16x32_f16(a0, b0, acc[0][0], 0, 0, 0);
    acc[0][1] = __builtin_amdgcn_mfma_f32_16x16x32_f16(a0, b1, acc[0][1], 0, 0, 0);
    acc[1][0] = __builtin_amdgcn_mfma_f32_16x16x32_f16(a1, b0, acc[1][0], 0, 0, 0);
    acc[1][1] = __builtin_amdgcn_mfma_f32_16x16x32_f16(a1, b1, acc[1][1], 0, 0, 0);
  }
  if constexpr (EPI == 0) {
    #pragma unroll
    for (int r = 0; r < 2; ++r)
      #pragma unroll
      for (int c = 0; c < 2; ++c) {
        int rowb = w * 32 + r * 16 + ((lane >> 4) << 2);
        int n = nb + c * 16 + (lane & 15);
        #pragma unroll
        for (int j = 0; j < 4; ++j)
          out[(size_t)(rowb + j) * NN + n] = acc[r][c][j] + bias[rowb + j];
      }
  } else if constexpr (EPI == 3) {
    #pragma unroll
    for (int r = 0; r < 2; ++r)
      #pragma unroll
      for (int c = 0; c < 2; ++c) {
        int rowb = w * 32 + r * 16 + ((lane >> 4) << 2);
        int n = nb + c * 16 + (lane & 15);
        float ss = 1e-6f;
        #pragma unroll
        for (int j = 0; j < 4; ++j) {
          float v = acc[r][c][j] + bias[rowb + j];
          ss += v * v;
        }
        out[(size_t)(rowb >> 2) * NN + n] = sqrtf(ss);
      }
  } else {
    __shared__ float tile[128][33];
    #pragma unroll
    for (int r = 0; r < 2; ++r)
      #pragma unroll
      for (int c = 0; c < 2; ++c) {
        int rowb = w * 32 + r * 16 + ((lane >> 4) << 2);
        int col = c * 16 + (lane & 15);
        #pragma unroll
        for (int j = 0; j < 4; ++j) tile[rowb + j][col] = acc[r][c][j];
      }
    __syncthreads();
    if constexpr (EPI == 1) {
      #pragma unroll
      for (int h = 0; h < 2; ++h) {
        int nl = (t & 15) + h * 16;
        int q = t >> 4;
        float v[8];
        #pragma unroll
        for (int j = 0; j < 8; ++j) v[j] = tile[q * 8 + j][nl] + bias[q * 8 + j];
        #pragma unroll
        for (int half = 0; half < 2; ++half) {
          float ss = 0.f;
          #pragma unroll
          for (int j = 0; j < 4; ++j) { float z = v[half * 4 + j]; ss += z * z; }
          float inv = 1.f / (sqrtf(ss) + 1e-6f);
          #pragma unroll
          for (int j = 0; j < 4; ++j) v[half * 4 + j] *= inv;
        }
        f16x8 fr;
        #pragma unroll
        for (int j = 0; j < 8; ++j) {
          out[(size_t)(q * 8 + j) * NN + nb + nl] = v[j];
          fr[j] = (f16)v[j];
        }
        *(f16x8*)(ofrag + nfrag_off(q * 8, nb + nl)) = fr;
      }
    } else {  // EPI == 2: Z adj-frags
      #pragma unroll
      for (int h = 0; h < 2; ++h) {
        int o = t & 127;
        int noct = (t >> 7) + h * 2;
        f16x8 fr;
        #pragma unroll
        for (int j = 0; j < 8; ++j) fr[j] = (f16)tile[o][noct * 8 + j];
        *(f16x8*)(ofrag + frag_off(8, o, nb + noct * 8)) = fr;
      }
    }
  }
}

// ---------------- fused: Kuramoto update + Z = Wc @ x4_new (per 16-node block) ------------
__global__ __launch_bounds__(256)
void kur_fin(const float* __restrict__ cb, const float* __restrict__ gnst,
             const float* __restrict__ gng, const float* __restrict__ gnb,
             const f16* __restrict__ wcfrag, float* __restrict__ x4,
             f16* __restrict__ x4frag, f16* __restrict__ zfrag) {
  __shared__ float lds[2664];
  f16* bf = (f16*)lds;                  // 4 k-tiles x 512 f16 (x4-new B-frags)
  f16* zt = (f16*)(lds + 1024);         // 128 x 24 f16 (Z tile)
  float* gmu = lds + 2600;
  float* grs = lds + 2632;
  const int t = threadIdx.x;
  const int lane = t & 63, w = t >> 6;
  if (t < 32) { gmu[t] = gnst[2*t]; grs[t] = gnst[2*t+1]; }
  __syncthreads();
  const int nb = blockIdx.x * 16;
  const int n = nb + (t & 15);
  const int q16 = t >> 4;
  float res[8];
  #pragma unroll
  for (int gi = 0; gi < 2; ++gi) {
    const int g = 2 * q16 + gi;
    const float mu = gmu[g], rstd = grs[g];
    float cn[4], xo[4];
    float inner = 0.f;
    #pragma unroll
    for (int o = 0; o < 4; ++o) {
      const int chn = 4 * g + o;
      float cv = (cb[(size_t)chn * NN + n] - mu) * rstd * gng[chn] + gnb[chn];
      float xv = x4[(size_t)chn * NN + n];
      cn[o] = cv; xo[o] = xv; inner += cv * xv;
    }
    float ssq = 0.f, xn[4];
    #pragma unroll
    for (int o = 0; o < 4; ++o) {
      xn[o] = xo[o] + (cn[o] - inner * xo[o]);
      ssq += xn[o] * xn[o];
    }
    float inv = 1.f / (sqrtf(ssq) + 1e-6f);
    #pragma unroll
    for (int o = 0; o < 4; ++o) {
      float vv = xn[o] * inv;
      res[gi * 4 + o] = vv;
      x4[(size_t)(4 * g + o) * NN + n] = vv;
    }
  }
  {
    f16x8 fr;
    #pragma unroll
    for (int j = 0; j < 8; ++j) fr[j] = (f16)res[j];
    *(f16x8*)(bf + (q16 >> 2) * 512 + (((n & 15) + 16 * (q16 & 3)) << 3)) = fr;
  }
  __syncthreads();
  // Z = Wc @ x4_new  (wave w: output rows 32w..32w+31)
  f32x4v za0 = (f32x4v){0,0,0,0}, za1 = (f32x4v){0,0,0,0};
  #pragma unroll
  for (int kt = 0; kt < 4; ++kt) {
    f16x8 a0 = *(const f16x8*)(wcfrag + ((size_t)(2 * w) * 4 + kt) * 512 + lane * 8);
    f16x8 a1 = *(const f16x8*)(wcfrag + ((size_t)(2 * w + 1) * 4 + kt) * 512 + lane * 8);
    f16x8 bv = *(const f16x8*)(bf + kt * 512 + lane * 8);
    za0 = __builtin_amdgcn_mfma_f32_16x16x32_f16(a0, bv, za0, 0, 0, 0);
    za1 = __builtin_amdgcn_mfma_f32_16x16x32_f16(a1, bv, za1, 0, 0, 0);
  }
  const int colz = lane & 15;
  const int rz = (lane >> 4) << 2;
  #pragma unroll
  for (int j = 0; j < 4; ++j) {
    zt[(w * 32 + rz + j) * 24 + colz]      = (f16)za0[j];
    zt[(w * 32 + 16 + rz + j) * 24 + colz] = (f16)za1[j];
  }
  __syncthreads();
  {
    const int ch = t & 127, noct = t >> 7;
    f16x8 fr = *(const f16x8*)(zt + ch * 24 + noct * 8);
    const int nn2 = nb + noct * 8;
    *(f16x8*)(zfrag + ((size_t)(nn2 >> 5) * 8 + (ch >> 4)) * 512
                    + (((ch & 15) + 16 * ((nn2 & 31) >> 3)) << 3)) = fr;
    const int kt = t >> 6, s2 = t & 63;
    *(f16x8*)(x4frag + ((size_t)kt * 256 + (nb >> 4)) * 512 + s2 * 8)
        = *(const f16x8*)(bf + kt * 512 + s2 * 8);
  }
}

// ---------------- fused readout tail: logits = (out_w @ ro_w2) @ mag + fused bias ----------
__global__ void head(const float* __restrict__ mag, const float* __restrict__ rw2,
                     const float* __restrict__ rb2, const float* __restrict__ ow,
                     const float* __restrict__ ob, float* __restrict__ out) {
  __shared__ float fw[4][32];
  __shared__ float fb[4];
  const int t = threadIdx.x;
  if (t < 128) {
    const int k = t >> 5, m = t & 31;
    float s = 0.f;
    for (int o = 0; o < 128; ++o) s += ow[k * 128 + o] * rw2[o * 32 + m];
    fw[k][m] = s;
  } else if (t < 132) {
    const int k = t - 128;
    float s = ob[k];
    for (int o = 0; o < 128; ++o) s += ow[k * 128 + o] * rb2[o];
    fb[k] = s;
  }
  __syncthreads();
  const int n = blockIdx.x * 256 + t;
  float a0 = fb[0], a1 = fb[1], a2 = fb[2], a3 = fb[3];
  for (int m = 0; m < 32; ++m) {
    float v = mag[(size_t)m * NN + n];
    a0 += fw[0][m] * v; a1 += fw[1][m] * v; a2 += fw[2][m] * v; a3 += fw[3][m] * v;
  }
  f4 r; r.x = a0; r.y = a1; r.z = a2; r.w = a3;
  ((f4*)out)[n] = r;
}

extern "C" void kernel_launch(void* const* d_in, const int* in_sizes, int n_in,
                              void* d_out, int out_size, void* d_ws, size_t ws_size,
                              hipStream_t stream) {
  const float* x      = (const float*)d_in[0];
  const float* adj    = (const float*)d_in[1];
  const float* mc_w0  = (const float*)d_in[2];
  const float* mc_b0  = (const float*)d_in[3];
  const float* mc_w1  = (const float*)d_in[4];
  const float* mc_b1  = (const float*)d_in[5];
  const float* mc_w2  = (const float*)d_in[6];
  const float* mc_b2  = (const float*)d_in[7];
  const float* mc_w3  = (const float*)d_in[8];
  const float* mc_b3  = (const float*)d_in[9];
  const float* proj_w = (const float*)d_in[10];
  const float* proj_b = (const float*)d_in[11];
  const float* pat_w  = (const float*)d_in[12];
  const float* pat_b  = (const float*)d_in[13];
  const float* kur_wc = (const float*)d_in[14];
  const float* kur_bc = (const float*)d_in[15];
  const float* kur_wy = (const float*)d_in[16];
  const float* kur_by = (const float*)d_in[17];
  const float* gn_g   = (const float*)d_in[18];
  const float* gn_b   = (const float*)d_in[19];
  const float* ro_w1  = (const float*)d_in[20];
  const float* ro_b1  = (const float*)d_in[21];
  const float* ro_w2  = (const float*)d_in[22];
  const float* ro_b2  = (const float*)d_in[23];
  const float* out_w  = (const float*)d_in[24];
  const float* out_b  = (const float*)d_in[25];
  float* out = (float*)d_out;
  float* Wf = (float*)d_ws;

  // ---- workspace layout (float-word offsets), ~67.4 MB (unchanged footprint) ----
  f16*   adj16    = (f16*)d_ws;                  // 32 MB
  float* csp      = Wf + 8388608;                // colsum partials (1 MB x4) in old part region
  float* statp    = Wf + 8388608 + 1048576;      // 256 KB stats partials (region dead post-convert)
  f16*   fragN    = (f16*)(Wf + 10485760);       // 3.5 MB (im2col; then fragA1/fragB1; then gst frags)
  f16*   fragA1   = fragN;                       //   0.5 MB alias (im2col dead after cy GEMM)
  f16*   fragB1   = fragN + 262144;              //   1 MB alias
  f16*   fragA0   = (f16*)(Wf + 11403264);       // 0.5 MB
  f16*   fragB0   = (f16*)(Wf + 11534336);       // 1 MB
  float* xT       = Wf + 11796480;               // 1 MB
  float* A1       = Wf + 12058624;               // 1 MB
  float* A2       = Wf + 12320768;               // 1 MB (magb alias)
  float* s1cat    = Wf + 12582912;               // 2 MB
  float* B1       = Wf + 13107200;               // 2 MB (wpart/Weff alias, early)
  float* wpart    = B1;
  float* Weff     = Wf + 13238272;
  float* B2       = Wf + 13631488;               // 2 MB
  float* gstf     = Wf + 14155776;               // 7 MB; alias after gst2frag:
  float* cbuf     = gstf;                        //   2 MB
  float* x4       = Wf + 14680064;               // 2 MB
  f16*   x4frag   = (f16*)(Wf + 15204352);       // 1 MB
  float* cy       = Wf + 15990784;               // 2 MB
  f16*   zfrag    = (f16*)(Wf + 16515072);       // 1 MB
  f16*   wcyfrag  = (f16*)(Wf + 16777216);       // 112 KB
  f16*   patfrag  = (f16*)(Wf + 16805888);       // 112 KB
  f16*   wcfrag   = (f16*)(Wf + 16834560);       // 32 KB
  f16*   row1frag = (f16*)(Wf + 16842752);       // 32 KB
  float* deg      = Wf + 16850944;               // 16 KB
  float* beff     = Wf + 16855040;               // 128
  float* cyb      = Wf + 16855168;               // 128
  float* gnst     = Wf + 16855296;               // 64
  float* magb     = A2;

  dim3 b256(256), b512(512);

  // 1. adj -> fp16 A-frags + degree
  convert_cs2<<<dim3(128, 8), b256, 0, stream>>>(adj, adj16, csp);
  colsum_fin<<<dim3(16), b256, 0, stream>>>(csp, deg);

  // 2. weight folds
  wfold1<<<dim3(16), b256, 0, stream>>>(proj_w, mc_w0, mc_w1, mc_w2, mc_w3, wpart);
  wfold_asm<<<dim3(32), b256, 0, stream>>>(wpart, proj_w, proj_b,
                                           mc_b0, mc_b1, mc_b2, mc_b3, Weff, beff);
  wfold2<<<dim3(14), b256, 0, stream>>>(kur_wy, Weff, beff, kur_by, kur_bc, wcyfrag, cyb);
  wprep<<<dim3(352), b256, 0, stream>>>(pat_w, kur_wc, ro_w1, patfrag, wcfrag, row1frag);

  // 3. x transpose + frags; im2col; cy = conv(x, Wcy) + cyb
  transpose_x<<<dim3(64), b256, 0, stream>>>(x, deg, xT, gstf, fragA0);
  im2col<<<dim3(896), b256, 0, stream>>>(x, fragN);
  wgemm<14, 0><<<dim3(128), b256, 0, stream>>>(wcyfrag, fragN, cyb, cy, nullptr);

  // 4. GST first order (F=64, full-K fused; frag ping-pong A0<->A1)
  adjfull<4, false><<<dim3(256), b512, 0, stream>>>(adj16, fragA0, xT, xT, A1, fragA1, 4,
                                                    fragB0, 0, gstf, 1, 1, s1cat, deg, nullptr, nullptr);
  adjfull<4, false><<<dim3(256), b512, 0, stream>>>(adj16, fragA1, A1, A1, A2, fragA0, 4,
                                                    fragB0, 64, gstf, 2, 2, s1cat + (size_t)64 * NN, deg, nullptr, nullptr);
  adjfull<4, false><<<dim3(256), b512, 0, stream>>>(adj16, fragA0, A2, nullptr, A1, fragA1, 4,
                                                    nullptr, 0, nullptr, -1, -1, nullptr, deg, nullptr, nullptr);
  adjfull<4, false><<<dim3(256), b512, 0, stream>>>(adj16, fragA1, A1, A2, A1, nullptr, 4,
                                                    nullptr, 0, gstf, 3, 3, nullptr, deg, nullptr, nullptr);

  // 5. GST second order (F=128, batched [s1_0|s1_1]; frag ping-pong B0<->B1)
  adjfull<8, false><<<dim3(256), b512, 0, stream>>>(adj16, fragB0, s1cat, nullptr, B1, fragB1, 8,
                                                    nullptr, 0, nullptr, -1, -1, nullptr, deg, nullptr, nullptr);
  adjfull<8, false><<<dim3(256), b512, 0, stream>>>(adj16, fragB1, B1, B1, B2, fragB0, 8,
                                                    nullptr, 0, gstf, 4, -1, nullptr, deg, nullptr, nullptr);
  adjfull<8, false><<<dim3(256), b512, 0, stream>>>(adj16, fragB0, B2, nullptr, B1, fragB1, 8,
                                                    nullptr, 0, nullptr, -1, -1, nullptr, deg, nullptr, nullptr);
  adjfull<8, false><<<dim3(256), b512, 0, stream>>>(adj16, fragB1, B1, B2, B1, nullptr, 8,
                                                    nullptr, 0, gstf, 5, 6, nullptr, deg, nullptr, nullptr);

  // 6. gst -> n-frags; x0 GEMM + osc-norm; Z0
  gst2frag<<<dim3(64, 7), b256, 0, stream>>>(gstf, fragN);
  wgemm<14, 1><<<dim3(128), b256, 0, stream>>>(patfrag, fragN, pat_b, x4, x4frag);
  wgemm<4, 2><<<dim3(128), b256, 0, stream>>>(wcfrag, x4frag, nullptr, nullptr, zfrag);

  // 7. Kuramoto dynamics: adjfull(kur) + statsfin + kur_fin per iteration
  for (int q = 0; q < 8; ++q) {
    adjfull<8, true><<<dim3(256), b512, 0, stream>>>(adj16, zfrag, nullptr, nullptr, cbuf,
                                                     nullptr, 0, nullptr, 0, nullptr, -1, -1,
                                                     nullptr, deg, cy, statp);
    statsfin<<<dim3(1), b256, 0, stream>>>(statp, gnst);
    kur_fin<<<dim3(256), b256, 0, stream>>>(cbuf, gnst, gn_g, gn_b, wcfrag,
                                            x4, x4frag, zfrag);
  }

  // 8. readout magnitude + fused head
  wgemm<4, 3><<<dim3(128), b256, 0, stream>>>(row1frag, x4frag, ro_b1, magb, nullptr);
  head<<<dim3(16), b256, 0, stream>>>(magb, ro_w2, ro_b2, out_w, out_b, out);
}

// Round 10
// 465.643 us; speedup vs baseline: 1.5787x; 1.5787x over previous
//
#include <hip/hip_runtime.h>
#include <math.h>

#define NN 4096

typedef float4 f4;
typedef _Float16 f16;
typedef _Float16 f16x8 __attribute__((ext_vector_type(8)));
typedef _Float16 h4 __attribute__((ext_vector_type(4)));
typedef float f32x4v __attribute__((ext_vector_type(4)));

// adjmm-convention B-frag offset (f16 units): ch = output column, n = reduction (node)
__device__ __forceinline__ size_t frag_off(int CT, int ch, int n) {
  return ((size_t)(n >> 5) * CT + (ch >> 4)) * 512
       + (size_t)((((ch & 15) + (((n & 31) >> 3) << 4)) << 3) + (n & 7));
}
// n-convention B-frag (for wgemm): col = node n (4096 wide -> CT=256), k = feature
__device__ __forceinline__ size_t nfrag_off(int k, int n) {
  return ((size_t)(k >> 5) * 256 + (n >> 4)) * 512
       + (size_t)((((n & 15) + (((k & 31) >> 3) << 4)) << 3) + (k & 7));
}
// A-frag offset (weights, M=128): row o, reduction k
__device__ __forceinline__ size_t afrag_off(int K32, int o, int k) {
  return ((size_t)(o >> 4) * K32 + (k >> 5)) * 512
       + (size_t)((((o & 15) + (((k & 31) >> 3) << 4)) << 3) + (k & 7));
}

// ---------------- adj fp32 -> fp16 A-frags (LDS-staged, coalesced) + colsum partials -------
__global__ __launch_bounds__(256)
void convert_cs2(const float* __restrict__ adj, f16* __restrict__ adj16,
                 float* __restrict__ csp) {
  __shared__ f16 lds16[32][520];
  const int rb = blockIdx.x;        // 128 blocks of 32 rows
  const int cb = blockIdx.y;        // 8 col blocks of 512
  const int t = threadIdx.x;
  const int half = t >> 7;          // 2 row halves of 16
  const int u = t & 127;
  const int c0 = cb * 512 + u * 4;
  float cs0 = 0.f, cs1 = 0.f, cs2 = 0.f, cs3 = 0.f;
  #pragma unroll 4
  for (int r = 0; r < 16; ++r) {
    const int i = rb * 32 + half * 16 + r;
    f4 v = *(const f4*)(adj + (size_t)i * NN + c0);
    cs0 += v.x; cs1 += v.y; cs2 += v.z; cs3 += v.w;
    h4 hv; hv[0] = (f16)v.x; hv[1] = (f16)v.y; hv[2] = (f16)v.z; hv[3] = (f16)v.w;
    *(h4*)&lds16[half * 16 + r][u * 4] = hv;
  }
  f4 cv; cv.x = cs0; cv.y = cs1; cv.z = cs2; cv.w = cs3;
  *(f4*)(csp + (size_t)(rb * 2 + half) * NN + c0) = cv;
  __syncthreads();
  const int rt = rb * 2 + half;
  f16* dst = adj16 + ((size_t)rt * 128 + cb * 16) * 512;
  #pragma unroll
  for (int s = 0; s < 8; ++s) {
    const int e = s * 1024 + u * 8;
    const int bl = e >> 9;
    const int l = (e >> 3) & 63;
    const int row = half * 16 + (l & 15);
    const int col = bl * 32 + (l >> 4) * 8;
    f16x8 fr = *(const f16x8*)&lds16[row][col];
    *(f16x8*)(dst + e) = fr;
  }
}

__global__ void colsum_fin(const float* __restrict__ csp, float* __restrict__ deg_inv) {
  int j = blockIdx.x * 256 + threadIdx.x;
  float s = 0.f;
  for (int rb = 0; rb < 256; ++rb) s += csp[(size_t)rb * NN + j];
  deg_inv[j] = 1.0f / (s + 1e-6f);
}

// ---------------- weight fold 1: per (branch, tap) GEMM into wpart ----------------
__global__ __launch_bounds__(256)
void wfold1(const float* __restrict__ proj_w,
            const float* __restrict__ w0, const float* __restrict__ w1,
            const float* __restrict__ w2, const float* __restrict__ w3,
            float* __restrict__ wpart) {
  __shared__ float projs[128][65];
  __shared__ float wk[64][65];
  const int b = blockIdx.x;
  int br, kp;
  if (b == 0) { br = 0; kp = 0; }
  else if (b < 4) { br = 1; kp = b - 1; }
  else if (b < 9) { br = 2; kp = b - 4; }
  else { br = 3; kp = b - 9; }
  const int Kbr = 2 * br + 1;
  const float* Wbr = (br == 0) ? w0 : (br == 1) ? w1 : (br == 2) ? w2 : w3;
  const int baseo[4] = {0, 8192, 32768, 73728};
  const int t = threadIdx.x;
  #pragma unroll
  for (int r = 0; r < 32; ++r) {
    int e = r * 256 + t; int o = e >> 6, cp = e & 63;
    projs[o][cp] = proj_w[(size_t)o * 256 + br * 64 + cp];
  }
  #pragma unroll
  for (int r = 0; r < 16; ++r) {
    int e = r * 256 + t; int cp = e >> 6, c = e & 63;
    wk[cp][c] = Wbr[(size_t)(cp * 64 + c) * Kbr + kp];
  }
  __syncthreads();
  for (int i = 0; i < 32; ++i) {
    int e = i * 256 + t; int o = e >> 6, c = e & 63;
    float s = 0.f;
    #pragma unroll 8
    for (int cp = 0; cp < 64; ++cp) s += projs[o][cp] * wk[cp][c];
    wpart[baseo[br] + (size_t)(o * 64 + c) * Kbr + kp] = s;
  }
}

// ---------------- weight fold assemble: Weff[o][c][7] + beff ----------------
__global__ void wfold_asm(const float* __restrict__ wpart, const float* __restrict__ proj_w,
                          const float* __restrict__ proj_b,
                          const float* __restrict__ b0, const float* __restrict__ b1,
                          const float* __restrict__ b2, const float* __restrict__ b3,
                          float* __restrict__ Weff, float* __restrict__ beff) {
  const int id = blockIdx.x * 256 + threadIdx.x;
  const int o = id >> 6, c = id & 63;
  const int oc = o * 64 + c;
  #pragma unroll
  for (int k = 0; k < 7; ++k) {
    float s = 0.f;
    if (k == 3)            s += wpart[oc];
    if (k >= 2 && k <= 4)  s += wpart[8192  + oc * 3 + (k - 2)];
    if (k >= 1 && k <= 5)  s += wpart[32768 + oc * 5 + (k - 1)];
    s += wpart[73728 + oc * 7 + k];
    Weff[(size_t)oc * 7 + k] = s;
  }
  if (blockIdx.x == 0 && threadIdx.x < 128) {
    const int oo = threadIdx.x;
    float s = proj_b[oo];
    for (int j = 0; j < 64; ++j) {
      s += proj_w[(size_t)oo * 256 + j] * b0[j];
      s += proj_w[(size_t)oo * 256 + 64 + j] * b1[j];
      s += proj_w[(size_t)oo * 256 + 128 + j] * b2[j];
      s += proj_w[(size_t)oo * 256 + 192 + j] * b3[j];
    }
    beff[oo] = s;
  }
}

// ---------------- weight fold 2: Wcy = kur_wy @ Weff -> f16 A-frags; cyb ----------------
__global__ __launch_bounds__(256)
void wfold2(const float* __restrict__ kur_wy, const float* __restrict__ Weff,
            const float* __restrict__ beff, const float* __restrict__ kur_by,
            const float* __restrict__ kur_bc,
            f16* __restrict__ wcyfrag, float* __restrict__ cyb) {
  __shared__ float wyh[128][65];
  __shared__ float weffL[128][33];
  const int ckb = blockIdx.x * 32;
  const int t = threadIdx.x;
  const int o = t & 127, hh = t >> 7;
  #pragma unroll
  for (int r = 0; r < 16; ++r) {
    int e = r * 256 + t; int op = e >> 5, ck = e & 31;
    weffL[op][ck] = Weff[(size_t)op * 448 + ckb + ck];
  }
  float acc[16];
  #pragma unroll
  for (int i = 0; i < 16; ++i) acc[i] = 0.f;
  float bacc = 0.f;
  for (int h = 0; h < 2; ++h) {
    __syncthreads();
    #pragma unroll
    for (int r = 0; r < 32; ++r) {
      int e = r * 256 + t; int oo = e >> 6, o2 = e & 63;
      wyh[oo][o2] = kur_wy[(size_t)oo * 128 + h * 64 + o2];
    }
    __syncthreads();
    for (int oo = 0; oo < 64; ++oo) {
      float w = wyh[o][oo];
      int op = h * 64 + oo;
      #pragma unroll
      for (int i = 0; i < 16; ++i) acc[i] += w * weffL[op][hh * 16 + i];
      if (t < 128) bacc += w * beff[op];
    }
  }
  #pragma unroll
  for (int i = 0; i < 16; ++i) {
    int ck = ckb + hh * 16 + i;
    int c = ck / 7, kt = ck % 7;
    wcyfrag[afrag_off(14, o, kt * 64 + c)] = (f16)acc[i];
  }
  if (blockIdx.x == 0 && t < 128) cyb[t] = bacc + kur_by[t] + kur_bc[t];
}

// ---------------- convert pat_w / kur_wc / ro_w1 to f16 A-frags ----------------
__global__ void wprep(const float* __restrict__ pat_w, const float* __restrict__ kur_wc,
                      const float* __restrict__ ro_w1,
                      f16* __restrict__ patfrag, f16* __restrict__ wcfrag,
                      f16* __restrict__ row1frag) {
  const int id = blockIdx.x * 256 + threadIdx.x;
  if (id < 57344) {
    int o = id / 448, k = id % 448;
    patfrag[afrag_off(14, o, k)] = (f16)pat_w[id];
  } else if (id < 73728) {
    int e = id - 57344; int o = e >> 7, k = e & 127;
    wcfrag[afrag_off(4, o, k)] = (f16)kur_wc[e];
  } else {
    int e = id - 73728; int o = e >> 7, k = e & 127;
    row1frag[afrag_off(4, o, k)] = (f16)ro_w1[e];
  }
}

// ---------------- x[N,64] -> xT[64][N] + gst coef0 row + fragA (x*deg_inv) ----------------
__global__ void transpose_x(const float* __restrict__ x, const float* __restrict__ deg,
                            float* __restrict__ xT, float* __restrict__ gst,
                            f16* __restrict__ fragA) {
  __shared__ float T[64][65];
  const int nb = blockIdx.x * 64;
  const int t = threadIdx.x;
  #pragma unroll
  for (int r = 0; r < 16; ++r) {
    int e = r * 256 + t; int nl = e >> 6, f = e & 63;
    T[nl][f] = x[(size_t)(nb + nl) * 64 + f];
  }
  __syncthreads();
  #pragma unroll
  for (int r = 0; r < 16; ++r) {
    int e = r * 256 + t; int f = e >> 6, nl = e & 63;
    float v = T[nl][f];
    xT[(size_t)f * NN + nb + nl] = v;
    gst[(size_t)f * 7 * NN + nb + nl] = v;
  }
  #pragma unroll
  for (int k = 0; k < 2; ++k) {
    int fi = k * 256 + t;
    int f = fi >> 3, n0l = (fi & 7) << 3;
    f16x8 fr;
    #pragma unroll
    for (int j = 0; j < 8; ++j) fr[j] = (f16)(T[n0l + j][f] * deg[nb + n0l + j]);
    *(f16x8*)(fragA + frag_off(4, f, nb + n0l)) = fr;
  }
}

// ---------------- im2col: x -> n-frags [k = dk*64+c][n], zero-padded ----------------
__global__ void im2col(const float* __restrict__ x, f16* __restrict__ fragN) {
  const int ot = blockIdx.x * 256 + threadIdx.x;
  const int q = ot >> 12;
  const int n = ot & 4095;
  const int dk = q >> 3;
  const int c0 = (q & 7) * 8;
  const int np = n + dk - 3;
  f16x8 fr;
  if (np >= 0 && np < NN) {
    const float* src = x + (size_t)np * 64 + c0;
    f4 v0 = *(const f4*)src, v1 = *(const f4*)(src + 4);
    fr[0]=(f16)v0.x; fr[1]=(f16)v0.y; fr[2]=(f16)v0.z; fr[3]=(f16)v0.w;
    fr[4]=(f16)v1.x; fr[5]=(f16)v1.y; fr[6]=(f16)v1.z; fr[7]=(f16)v1.w;
  } else {
    #pragma unroll
    for (int j = 0; j < 8; ++j) fr[j] = (f16)0.f;
  }
  *(f16x8*)(fragN + nfrag_off(q * 8, n)) = fr;
}

// ---------------- MFMA split-K GEMM vs adjacency, v3: 16-row tiles, 2-step LDS reduce -----
// block b: rows (b&255)*16..+16, K-chunk kz = b>>8; 4 waves split the block's K-range.
// LDS = 2*CT*256 floats (16 KB for F=128, 8 KB for F=64) -> 4-8 blocks/CU, 16-32 waves/CU.
template<int F, int KZ>
__global__ __launch_bounds__(256)
void adjmm16(const f16* __restrict__ adj16, const f16* __restrict__ rhs,
             float* __restrict__ part) {
  constexpr int CT = F / 16;
  constexpr int KSB = (NN / KZ) / 32;   // K-steps per block
  constexpr int KS = KSB / 4;           // K-steps per wave
  const int t = threadIdx.x;
  const int lane = t & 63, w = t >> 6;
  const int mt = blockIdx.x & 255;      // 16-row tile
  const int kz = blockIdx.x >> 8;
  const int kt0 = kz * KSB + w * KS;
  const size_t aoff = ((size_t)mt * 128 + kt0) * 512 + (size_t)lane * 8;
  const f16* bb = rhs + (size_t)kt0 * CT * 512 + lane * 8;
  f32x4v acc[CT];
  #pragma unroll
  for (int c = 0; c < CT; ++c) acc[c] = (f32x4v){0.f, 0.f, 0.f, 0.f};
  #pragma unroll 2
  for (int i = 0; i < KS; ++i) {
    f16x8 a = *(const f16x8*)(adj16 + aoff + (size_t)i * 512);
    #pragma unroll
    for (int c = 0; c < CT; ++c) {
      f16x8 bv = *(const f16x8*)(bb + ((size_t)i * CT + c) * 512);
      acc[c] = __builtin_amdgcn_mfma_f32_16x16x32_f16(a, bv, acc[c], 0, 0, 0);
    }
  }
  __shared__ float redf[2 * CT * 256];
  // step 1: waves 2,3 store
  if (w >= 2) {
    float* myw = redf + (w - 2) * (CT * 256);
    #pragma unroll
    for (int c = 0; c < CT; ++c) *(f32x4v*)(myw + c * 256 + lane * 4) = acc[c];
  }
  __syncthreads();
  // step 2: waves 0,1 add partner (w+2) and store
  if (w < 2) {
    float* myw = redf + w * (CT * 256);
    #pragma unroll
    for (int c = 0; c < CT; ++c) {
      acc[c] += *(const f32x4v*)(myw + c * 256 + lane * 4);
      *(f32x4v*)(myw + c * 256 + lane * 4) = acc[c];
    }
  }
  __syncthreads();
  float* pb = part + (size_t)kz * F * NN;
  constexpr int SLOTS = CT * 64;        // f4 slots (16 nodes x F ch / 4)
  #pragma unroll
  for (int s = 0; s < SLOTS; s += 256) {
    const int slot = s + t;
    f32x4v v = *(const f32x4v*)(redf + slot * 4);
    v += *(const f32x4v*)(redf + CT * 256 + slot * 4);
    const int ct = slot >> 6, l = slot & 63;
    const int ch = ct * 16 + (l & 15);
    const int node0 = mt * 16 + ((l >> 4) << 2);
    *(f32x4v*)(pb + (size_t)ch * NN + node0) = v;
  }
}

// ---------------- reduce split-K + P epilogue + frag/diff/gst/s1 fusion (f4/thread) -------
__global__ void reduce_P(const float* __restrict__ part, const float* __restrict__ u,
                         const float* __restrict__ D, float* __restrict__ outp,
                         f16* __restrict__ fragNext, int nextCT,
                         f16* __restrict__ fragDiff, int diffChOff,
                         float* __restrict__ gstf, int coefLo, int coefHi,
                         float* __restrict__ s1buf, const float* __restrict__ deg,
                         int F, int KZ) {
  const int id = blockIdx.x * 256 + threadIdx.x;
  const int ch = id >> 10, n0 = (id & 1023) << 2;
  const size_t base = (size_t)ch * NN + n0;
  float a0 = 0.f, a1 = 0.f, a2 = 0.f, a3 = 0.f;
  for (int z = 0; z < KZ; ++z) {
    f4 p = *(const f4*)(part + (size_t)z * F * NN + base);
    a0 += p.x; a1 += p.y; a2 += p.z; a3 += p.w;
  }
  f4 u0 = *(const f4*)(u + base);
  float o0 = 0.5f * (u0.x + a0), o1 = 0.5f * (u0.y + a1);
  float o2 = 0.5f * (u0.z + a2), o3 = 0.5f * (u0.w + a3);
  f4 ov; ov.x = o0; ov.y = o1; ov.z = o2; ov.w = o3;
  *(f4*)(outp + base) = ov;
  if (fragNext) {
    f4 dg = *(const f4*)(deg + n0);
    h4 fr;
    fr[0] = (f16)(o0 * dg.x); fr[1] = (f16)(o1 * dg.y);
    fr[2] = (f16)(o2 * dg.z); fr[3] = (f16)(o3 * dg.w);
    *(h4*)(fragNext + frag_off(nextCT, ch, n0)) = fr;
  }
  if (D) {
    f4 d0 = *(const f4*)(D + base);
    float e0 = fabsf(d0.x - o0), e1 = fabsf(d0.y - o1);
    float e2 = fabsf(d0.z - o2), e3 = fabsf(d0.w - o3);
    f4 ev; ev.x = e0; ev.y = e1; ev.z = e2; ev.w = e3;
    if (s1buf) *(f4*)(s1buf + base) = ev;
    if (fragDiff) {
      f4 dg = *(const f4*)(deg + n0);
      h4 fr;
      fr[0] = (f16)(e0 * dg.x); fr[1] = (f16)(e1 * dg.y);
      fr[2] = (f16)(e2 * dg.z); fr[3] = (f16)(e3 * dg.w);
      *(h4*)(fragDiff + frag_off(8, diffChOff + ch, n0)) = fr;
    }
    if (gstf) {
      int coef = (ch < 64) ? coefLo : coefHi;
      if (coef >= 0)
        *(f4*)(gstf + (size_t)((ch & 63) * 7 + coef) * NN + n0) = ev;
    }
  }
}

// ---------------- gstf fp32 rows -> n-frags (LDS transpose) ----------------
__global__ void gst2frag(const float* __restrict__ gstf, f16* __restrict__ fragN) {
  __shared__ float T[64][65];
  const int nb = blockIdx.x * 64;
  const int kb = blockIdx.y * 64;
  const int t = threadIdx.x;
  #pragma unroll
  for (int r = 0; r < 16; ++r) {
    int e = r * 256 + t; int row = e >> 6, col = e & 63;
    T[row][col] = gstf[(size_t)(kb + row) * NN + nb + col];
  }
  __syncthreads();
  #pragma unroll
  for (int h = 0; h < 2; ++h) {
    int idx = h * 256 + t;
    int q = idx >> 6, n = idx & 63;
    f16x8 fr;
    #pragma unroll
    for (int j = 0; j < 8; ++j) fr[j] = (f16)T[q * 8 + j][n];
    *(f16x8*)(fragN + nfrag_off(kb + q * 8, nb + n)) = fr;
  }
}

// ---------------- generic MFMA wgemm (EPI 0/1/2/3 as before) ----------------
template<int K32, int EPI>
__global__ __launch_bounds__(256)
void wgemm(const f16* __restrict__ A, const f16* __restrict__ B,
           const float* __restrict__ bias, float* __restrict__ out,
           f16* __restrict__ ofrag) {
  const int t = threadIdx.x;
  const int lane = t & 63, w = t >> 6;
  const int nb = blockIdx.x * 32;
  const size_t a0b = ((size_t)(2 * w) * K32) * 512 + lane * 8;
  const size_t a1b = ((size_t)(2 * w + 1) * K32) * 512 + lane * 8;
  const size_t b0b = (size_t)(nb >> 4) * 512 + lane * 8;
  f32x4v acc[2][2];
  acc[0][0] = (f32x4v){0,0,0,0}; acc[0][1] = (f32x4v){0,0,0,0};
  acc[1][0] = (f32x4v){0,0,0,0}; acc[1][1] = (f32x4v){0,0,0,0};
  #pragma unroll
  for (int i = 0; i < K32; ++i) {
    f16x8 a0 = *(const f16x8*)(A + a0b + (size_t)i * 512);
    f16x8 a1 = *(const f16x8*)(A + a1b + (size_t)i * 512);
    f16x8 b0 = *(const f16x8*)(B + b0b + (size_t)i * 256 * 512);
    f16x8 b1 = *(const f16x8*)(B + b0b + (size_t)i * 256 * 512 + 512);
    acc[0][0] = __builtin_amdgcn_mfma_f32_16x16x32_f16(a0, b0, acc[0][0], 0, 0, 0);
    acc[0][1] = __builtin_amdgcn_mfma_f32_16x16x32_f16(a0, b1, acc[0][1], 0, 0, 0);
    acc[1][0] = __builtin_amdgcn_mfma_f32_16x16x32_f16(a1, b0, acc[1][0], 0, 0, 0);
    acc[1][1] = __builtin_amdgcn_mfma_f32_16x16x32_f16(a1, b1, acc[1][1], 0, 0, 0);
  }
  if constexpr (EPI == 0) {
    #pragma unroll
    for (int r = 0; r < 2; ++r)
      #pragma unroll
      for (int c = 0; c < 2; ++c) {
        int rowb = w * 32 + r * 16 + ((lane >> 4) << 2);
        int n = nb + c * 16 + (lane & 15);
        #pragma unroll
        for (int j = 0; j < 4; ++j)
          out[(size_t)(rowb + j) * NN + n] = acc[r][c][j] + bias[rowb + j];
      }
  } else if constexpr (EPI == 3) {
    #pragma unroll
    for (int r = 0; r < 2; ++r)
      #pragma unroll
      for (int c = 0; c < 2; ++c) {
        int rowb = w * 32 + r * 16 + ((lane >> 4) << 2);
        int n = nb + c * 16 + (lane & 15);
        float ss = 1e-6f;
        #pragma unroll
        for (int j = 0; j < 4; ++j) {
          float v = acc[r][c][j] + bias[rowb + j];
          ss += v * v;
        }
        out[(size_t)(rowb >> 2) * NN + n] = sqrtf(ss);
      }
  } else {
    __shared__ float tile[128][33];
    #pragma unroll
    for (int r = 0; r < 2; ++r)
      #pragma unroll
      for (int c = 0; c < 2; ++c) {
        int rowb = w * 32 + r * 16 + ((lane >> 4) << 2);
        int col = c * 16 + (lane & 15);
        #pragma unroll
        for (int j = 0; j < 4; ++j) tile[rowb + j][col] = acc[r][c][j];
      }
    __syncthreads();
    if constexpr (EPI == 1) {
      #pragma unroll
      for (int h = 0; h < 2; ++h) {
        int nl = (t & 15) + h * 16;
        int q = t >> 4;
        float v[8];
        #pragma unroll
        for (int j = 0; j < 8; ++j) v[j] = tile[q * 8 + j][nl] + bias[q * 8 + j];
        #pragma unroll
        for (int half = 0; half < 2; ++half) {
          float ss = 0.f;
          #pragma unroll
          for (int j = 0; j < 4; ++j) { float z = v[half * 4 + j]; ss += z * z; }
          float inv = 1.f / (sqrtf(ss) + 1e-6f);
          #pragma unroll
          for (int j = 0; j < 4; ++j) v[half * 4 + j] *= inv;
        }
        f16x8 fr;
        #pragma unroll
        for (int j = 0; j < 8; ++j) {
          out[(size_t)(q * 8 + j) * NN + nb + nl] = v[j];
          fr[j] = (f16)v[j];
        }
        *(f16x8*)(ofrag + nfrag_off(q * 8, nb + nl)) = fr;
      }
    } else {  // EPI == 2: Z adj-frags
      #pragma unroll
      for (int h = 0; h < 2; ++h) {
        int o = t & 127;
        int noct = (t >> 7) + h * 2;
        f16x8 fr;
        #pragma unroll
        for (int j = 0; j < 8; ++j) fr[j] = (f16)tile[o][noct * 8 + j];
        *(f16x8*)(ofrag + frag_off(8, o, nb + noct * 8)) = fr;
      }
    }
  }
}

// ---------------- reduce split-K + cy -> c ; per-channel sum/sumsq (round-5 proven) -------
__global__ __launch_bounds__(256)
void reduce_stats(const float* __restrict__ part, const float* __restrict__ cy,
                  float* __restrict__ c, float* __restrict__ statp) {
  const int ch = blockIdx.x;
  const int t = threadIdx.x;
  const size_t b4 = (size_t)ch * 1024;
  float s = 0.f, ss = 0.f;
  #pragma unroll
  for (int k = 0; k < 4; ++k) {
    const size_t idx = b4 + t + k * 256;
    f4 v = ((const f4*)cy)[idx];
    #pragma unroll
    for (int z = 0; z < 4; ++z) {
      f4 p = ((const f4*)part)[(size_t)z * 131072 + idx];
      v.x += p.x; v.y += p.y; v.z += p.z; v.w += p.w;
    }
    ((f4*)c)[idx] = v;
    s  += v.x + v.y + v.z + v.w;
    ss += v.x*v.x + v.y*v.y + v.z*v.z + v.w*v.w;
  }
  #pragma unroll
  for (int off = 32; off > 0; off >>= 1) { s += __shfl_down(s, off); ss += __shfl_down(ss, off); }
  __shared__ float rs[4], rss[4];
  if ((t & 63) == 0) { rs[t >> 6] = s; rss[t >> 6] = ss; }
  __syncthreads();
  if (t == 0) {
    statp[ch * 2]     = rs[0] + rs[1] + rs[2] + rs[3];
    statp[ch * 2 + 1] = rss[0] + rss[1] + rss[2] + rss[3];
  }
}

// ---------------- fused: GN stats fin + Kuramoto update + Z = Wc @ x4_new (per-block) ------
// block b owns 16 nodes; all 128 channels local -> Z-MFMA needs no cross-block data.
// zfrag == nullptr skips the Z computation (last iteration).
__global__ __launch_bounds__(256)
void kur_fin(const float* __restrict__ cb, const float* __restrict__ statp,
             const float* __restrict__ gng, const float* __restrict__ gnb,
             const f16* __restrict__ wcfrag, float* __restrict__ x4,
             f16* __restrict__ x4frag, f16* __restrict__ zfrag) {
  __shared__ float lds[2664];
  f16* bf = (f16*)lds;                  // 4 k-tiles x 512 f16 (x4-new B-frags)
  f16* zt = (f16*)(lds + 1024);         // 128 x 24 f16 (Z tile)
  float* gmu = lds + 2600;
  float* grs = lds + 2632;
  const int t = threadIdx.x;
  const int lane = t & 63, w = t >> 6;
  if (t < 32) {
    float s = 0.f, ss = 0.f;
    #pragma unroll
    for (int o = 0; o < 4; ++o) { s += statp[(4*t+o)*2]; ss += statp[(4*t+o)*2+1]; }
    float mu = s * (1.f / 16384.f);
    float var = ss * (1.f / 16384.f) - mu * mu;
    gmu[t] = mu;
    grs[t] = rsqrtf(var + 1e-5f);
  }
  __syncthreads();
  const int nb = blockIdx.x * 16;
  const int n = nb + (t & 15);
  const int q16 = t >> 4;
  float res[8];
  #pragma unroll
  for (int gi = 0; gi < 2; ++gi) {
    const int g = 2 * q16 + gi;
    const float mu = gmu[g], rstd = grs[g];
    float cn[4], xo[4];
    float inner = 0.f;
    #pragma unroll
    for (int o = 0; o < 4; ++o) {
      const int chn = 4 * g + o;
      float cv = (cb[(size_t)chn * NN + n] - mu) * rstd * gng[chn] + gnb[chn];
      float xv = x4[(size_t)chn * NN + n];
      cn[o] = cv; xo[o] = xv; inner += cv * xv;
    }
    float ssq = 0.f, xn[4];
    #pragma unroll
    for (int o = 0; o < 4; ++o) {
      xn[o] = xo[o] + (cn[o] - inner * xo[o]);
      ssq += xn[o] * xn[o];
    }
    float inv = 1.f / (sqrtf(ssq) + 1e-6f);
    #pragma unroll
    for (int o = 0; o < 4; ++o) {
      float vv = xn[o] * inv;
      res[gi * 4 + o] = vv;
      x4[(size_t)(4 * g + o) * NN + n] = vv;
    }
  }
  {
    f16x8 fr;
    #pragma unroll
    for (int j = 0; j < 8; ++j) fr[j] = (f16)res[j];
    *(f16x8*)(bf + (q16 >> 2) * 512 + (((n & 15) + 16 * (q16 & 3)) << 3)) = fr;
  }
  __syncthreads();
  // x4 n-frags (always)
  {
    const int kt = t >> 6, s2 = t & 63;
    *(f16x8*)(x4frag + ((size_t)kt * 256 + (nb >> 4)) * 512 + s2 * 8)
        = *(const f16x8*)(bf + kt * 512 + s2 * 8);
  }
  if (!zfrag) return;
  // Z = Wc @ x4_new  (wave w: output rows 32w..32w+31)
  f32x4v za0 = (f32x4v){0,0,0,0}, za1 = (f32x4v){0,0,0,0};
  #pragma unroll
  for (int kt = 0; kt < 4; ++kt) {
    f16x8 a0 = *(const f16x8*)(wcfrag + ((size_t)(2 * w) * 4 + kt) * 512 + lane * 8);
    f16x8 a1 = *(const f16x8*)(wcfrag + ((size_t)(2 * w + 1) * 4 + kt) * 512 + lane * 8);
    f16x8 bv = *(const f16x8*)(bf + kt * 512 + lane * 8);
    za0 = __builtin_amdgcn_mfma_f32_16x16x32_f16(a0, bv, za0, 0, 0, 0);
    za1 = __builtin_amdgcn_mfma_f32_16x16x32_f16(a1, bv, za1, 0, 0, 0);
  }
  const int colz = lane & 15;
  const int rz = (lane >> 4) << 2;
  #pragma unroll
  for (int j = 0; j < 4; ++j) {
    zt[(w * 32 + rz + j) * 24 + colz]      = (f16)za0[j];
    zt[(w * 32 + 16 + rz + j) * 24 + colz] = (f16)za1[j];
  }
  __syncthreads();
  {
    // 256 threads: ch = t&127, node-octet = t>>7 (2 octets x 8 = all 16 nodes)
    const int ch = t & 127, noct = t >> 7;
    f16x8 fr = *(const f16x8*)(zt + ch * 24 + noct * 8);
    const int nn2 = nb + noct * 8;
    *(f16x8*)(zfrag + ((size_t)(nn2 >> 5) * 8 + (ch >> 4)) * 512
                    + (((ch & 15) + 16 * ((nn2 & 31) >> 3)) << 3)) = fr;
  }
}

// ---------------- fused readout tail: logits = (out_w @ ro_w2) @ mag + fused bias ----------
__global__ void head(const float* __restrict__ mag, const float* __restrict__ rw2,
                     const float* __restrict__ rb2, const float* __restrict__ ow,
                     const float* __restrict__ ob, float* __restrict__ out) {
  __shared__ float fw[4][32];
  __shared__ float fb[4];
  const int t = threadIdx.x;
  if (t < 128) {
    const int k = t >> 5, m = t & 31;
    float s = 0.f;
    for (int o = 0; o < 128; ++o) s += ow[k * 128 + o] * rw2[o * 32 + m];
    fw[k][m] = s;
  } else if (t < 132) {
    const int k = t - 128;
    float s = ob[k];
    for (int o = 0; o < 128; ++o) s += ow[k * 128 + o] * rb2[o];
    fb[k] = s;
  }
  __syncthreads();
  const int n = blockIdx.x * 256 + t;
  float a0 = fb[0], a1 = fb[1], a2 = fb[2], a3 = fb[3];
  for (int m = 0; m < 32; ++m) {
    float v = mag[(size_t)m * NN + n];
    a0 += fw[0][m] * v; a1 += fw[1][m] * v; a2 += fw[2][m] * v; a3 += fw[3][m] * v;
  }
  f4 r; r.x = a0; r.y = a1; r.z = a2; r.w = a3;
  ((f4*)out)[n] = r;
}

extern "C" void kernel_launch(void* const* d_in, const int* in_sizes, int n_in,
                              void* d_out, int out_size, void* d_ws, size_t ws_size,
                              hipStream_t stream) {
  const float* x      = (const float*)d_in[0];
  const float* adj    = (const float*)d_in[1];
  const float* mc_w0  = (const float*)d_in[2];
  const float* mc_b0  = (const float*)d_in[3];
  const float* mc_w1  = (const float*)d_in[4];
  const float* mc_b1  = (const float*)d_in[5];
  const float* mc_w2  = (const float*)d_in[6];
  const float* mc_b2  = (const float*)d_in[7];
  const float* mc_w3  = (const float*)d_in[8];
  const float* mc_b3  = (const float*)d_in[9];
  const float* proj_w = (const float*)d_in[10];
  const float* proj_b = (const float*)d_in[11];
  const float* pat_w  = (const float*)d_in[12];
  const float* pat_b  = (const float*)d_in[13];
  const float* kur_wc = (const float*)d_in[14];
  const float* kur_bc = (const float*)d_in[15];
  const float* kur_wy = (const float*)d_in[16];
  const float* kur_by = (const float*)d_in[17];
  const float* gn_g   = (const float*)d_in[18];
  const float* gn_b   = (const float*)d_in[19];
  const float* ro_w1  = (const float*)d_in[20];
  const float* ro_b1  = (const float*)d_in[21];
  const float* ro_w2  = (const float*)d_in[22];
  const float* ro_b2  = (const float*)d_in[23];
  const float* out_w  = (const float*)d_in[24];
  const float* out_b  = (const float*)d_in[25];
  float* out = (float*)d_out;
  float* Wf = (float*)d_ws;

  // ---- workspace layout (float-word offsets), ~67.4 MB ----
  f16*   adj16    = (f16*)d_ws;                  // 32 MB
  float* part     = Wf + 8388608;                // 8 MB (csp alias)
  float* csp      = part;
  f16*   fragN    = (f16*)(Wf + 10485760);       // 3.5 MB (im2col, then gst frags)
  f16*   fragA    = (f16*)(Wf + 11403264);       // 0.5 MB
  f16*   fragB    = (f16*)(Wf + 11534336);       // 1 MB
  float* xT       = Wf + 11796480;               // 1 MB
  float* A1       = Wf + 12058624;               // 1 MB
  float* A2       = Wf + 12320768;               // 1 MB (magb alias)
  float* s1cat    = Wf + 12582912;               // 2 MB
  float* B1       = Wf + 13107200;               // 2 MB (wpart/Weff alias, early)
  float* wpart    = B1;
  float* Weff     = Wf + 13238272;
  float* B2       = Wf + 13631488;               // 2 MB
  float* gstf     = Wf + 14155776;               // 7 MB; alias after gst2frag:
  float* cbuf     = gstf;                        //   2 MB
  float* x4       = Wf + 14680064;               // 2 MB
  f16*   x4frag   = (f16*)(Wf + 15204352);       // 1 MB
  float* cy       = Wf + 15990784;               // 2 MB
  f16*   zfrag    = (f16*)(Wf + 16515072);       // 1 MB
  f16*   wcyfrag  = (f16*)(Wf + 16777216);       // 112 KB
  f16*   patfrag  = (f16*)(Wf + 16805888);       // 112 KB
  f16*   wcfrag   = (f16*)(Wf + 16834560);       // 32 KB
  f16*   row1frag = (f16*)(Wf + 16842752);       // 32 KB
  float* deg      = Wf + 16850944;               // 16 KB
  float* beff     = Wf + 16855040;               // 128
  float* cyb      = Wf + 16855168;               // 128
  float* statp    = Wf + 16855296;               // 256
  float* magb     = A2;

  dim3 b256(256);

  // 1. adj -> fp16 A-frags + degree
  convert_cs2<<<dim3(128, 8), b256, 0, stream>>>(adj, adj16, csp);
  colsum_fin<<<dim3(16), b256, 0, stream>>>(csp, deg);

  // 2. weight folds
  wfold1<<<dim3(16), b256, 0, stream>>>(proj_w, mc_w0, mc_w1, mc_w2, mc_w3, wpart);
  wfold_asm<<<dim3(32), b256, 0, stream>>>(wpart, proj_w, proj_b,
                                           mc_b0, mc_b1, mc_b2, mc_b3, Weff, beff);
  wfold2<<<dim3(14), b256, 0, stream>>>(kur_wy, Weff, beff, kur_by, kur_bc, wcyfrag, cyb);
  wprep<<<dim3(352), b256, 0, stream>>>(pat_w, kur_wc, ro_w1, patfrag, wcfrag, row1frag);

  // 3. x transpose + frags; im2col; cy = conv(x, Wcy) + cyb
  transpose_x<<<dim3(64), b256, 0, stream>>>(x, deg, xT, gstf, fragA);
  im2col<<<dim3(896), b256, 0, stream>>>(x, fragN);
  wgemm<14, 0><<<dim3(128), b256, 0, stream>>>(wcyfrag, fragN, cyb, cy, nullptr);

  // 4. GST first order (F=64, KZ=8; 2048-block adjmm, 256-block reduce)
  adjmm16<64, 8><<<dim3(2048), b256, 0, stream>>>(adj16, fragA, part);
  reduce_P<<<dim3(256), b256, 0, stream>>>(part, xT, xT, A1, fragA, 4,
                                           fragB, 0, gstf, 1, 1, s1cat, deg, 64, 8);
  adjmm16<64, 8><<<dim3(2048), b256, 0, stream>>>(adj16, fragA, part);
  reduce_P<<<dim3(256), b256, 0, stream>>>(part, A1, A1, A2, fragA, 4,
                                           fragB, 64, gstf, 2, 2, s1cat + (size_t)64 * NN, deg, 64, 8);
  adjmm16<64, 8><<<dim3(2048), b256, 0, stream>>>(adj16, fragA, part);
  reduce_P<<<dim3(256), b256, 0, stream>>>(part, A2, nullptr, A1, fragA, 4,
                                           nullptr, 0, nullptr, -1, -1, nullptr, deg, 64, 8);
  adjmm16<64, 8><<<dim3(2048), b256, 0, stream>>>(adj16, fragA, part);
  reduce_P<<<dim3(256), b256, 0, stream>>>(part, A1, A2, A1, nullptr, 4,
                                           nullptr, 0, gstf, 3, 3, nullptr, deg, 64, 8);

  // 5. GST second order (F=128, KZ=4; 1024-block adjmm, 512-block reduce)
  adjmm16<128, 4><<<dim3(1024), b256, 0, stream>>>(adj16, fragB, part);
  reduce_P<<<dim3(512), b256, 0, stream>>>(part, s1cat, nullptr, B1, fragB, 8,
                                           nullptr, 0, nullptr, -1, -1, nullptr, deg, 128, 4);
  adjmm16<128, 4><<<dim3(1024), b256, 0, stream>>>(adj16, fragB, part);
  reduce_P<<<dim3(512), b256, 0, stream>>>(part, B1, B1, B2, fragB, 8,
                                           nullptr, 0, gstf, 4, -1, nullptr, deg, 128, 4);
  adjmm16<128, 4><<<dim3(1024), b256, 0, stream>>>(adj16, fragB, part);
  reduce_P<<<dim3(512), b256, 0, stream>>>(part, B2, nullptr, B1, fragB, 8,
                                           nullptr, 0, nullptr, -1, -1, nullptr, deg, 128, 4);
  adjmm16<128, 4><<<dim3(1024), b256, 0, stream>>>(adj16, fragB, part);
  reduce_P<<<dim3(512), b256, 0, stream>>>(part, B1, B2, B1, nullptr, 8,
                                           nullptr, 0, gstf, 5, 6, nullptr, deg, 128, 4);

  // 6. gst -> n-frags; x0 GEMM + osc-norm; Z0
  gst2frag<<<dim3(64, 7), b256, 0, stream>>>(gstf, fragN);
  wgemm<14, 1><<<dim3(128), b256, 0, stream>>>(patfrag, fragN, pat_b, x4, x4frag);
  wgemm<4, 2><<<dim3(128), b256, 0, stream>>>(wcfrag, x4frag, nullptr, nullptr, zfrag);

  // 7. Kuramoto dynamics: 3 kernels/iter; last iter skips Z emission
  for (int q = 0; q < 8; ++q) {
    adjmm16<128, 4><<<dim3(1024), b256, 0, stream>>>(adj16, zfrag, part);
    reduce_stats<<<dim3(128), b256, 0, stream>>>(part, cy, cbuf, statp);
    kur_fin<<<dim3(256), b256, 0, stream>>>(cbuf, statp, gn_g, gn_b, wcfrag,
                                            x4, x4frag, (q < 7) ? zfrag : nullptr);
  }

  // 8. readout magnitude + fused head
  wgemm<4, 3><<<dim3(128), b256, 0, stream>>>(row1frag, x4frag, ro_b1, magb, nullptr);
  head<<<dim3(16), b256, 0, stream>>>(magb, ro_w2, ro_b2, out_w, out_b, out);
}